// Round 10
// baseline (292.328 us; speedup 1.0000x reference)
//
#include <hip/hip_runtime.h>

#define BATCH   4096
#define IN_F    1024
#define OUT_F   1024
#define KF      8
#define KD      14336          /* trimmed GEMM K-dim: (7 sin + 7 cos) * 1024, feature-major */

#define BM 128
#define BN 256
#define BK 64
#define KSPLIT 4
#define KCHUNK (KD/KSPLIT)     /* 3584 */
#define NT (KCHUNK/BK)         /* 56 K-tiles per block */
#define C_ELEMS ((size_t)BATCH * OUT_F)

typedef short short8 __attribute__((ext_vector_type(8)));
typedef float f32x4  __attribute__((ext_vector_type(4)));

// bf16 round-to-nearest-even from f32 (bit pattern in ushort)
__device__ __forceinline__ unsigned short f2bf(float f) {
  union { float f; unsigned int u; } v; v.f = f;
  unsigned int u = v.u;
  unsigned int lsb = (u >> 16) & 1u;
  u += 0x7fffu + lsb;
  return (unsigned short)(u >> 16);
}

__device__ __forceinline__ unsigned int pack2(float lo, float hi) {
  return (unsigned int)f2bf(lo) | ((unsigned int)f2bf(hi) << 16);
}

__device__ __forceinline__ void gload_lds16(const void* g, void* l) {
  __builtin_amdgcn_global_load_lds((const __attribute__((address_space(1))) void*)g,
                                   (__attribute__((address_space(3))) void*)l,
                                   16, 0, 0);
}

// ---------------- W conversion (k=0 trimmed, feature-major, i-pair) + bias ----------------
__global__ __launch_bounds__(256) void wconv_kernel(const float* __restrict__ a,
                                                    const float* __restrict__ b,
                                                    unsigned short* __restrict__ W,
                                                    float* __restrict__ bias) {
  int idx = blockIdx.x * 256 + threadIdx.x;
  int o  = idx >> 9;
  int i0 = (idx & 511) * 2;
  const float4* ap = reinterpret_cast<const float4*>(a + (size_t)o * 8192 + i0 * 8);
  const float4* bp = reinterpret_cast<const float4*>(b + (size_t)o * 8192 + i0 * 8);
  float4 a0 = ap[0], a1 = ap[1], a2 = ap[2], a3 = ap[3];
  float4 b0 = bp[0], b1 = bp[1], b2 = bp[2], b3 = bp[3];

  unsigned int* wp = reinterpret_cast<unsigned int*>(W + (size_t)o * KD + i0);
  wp[ 0 * IN_F / 2] = pack2(a0.y, a2.y);
  wp[ 1 * IN_F / 2] = pack2(a0.z, a2.z);
  wp[ 2 * IN_F / 2] = pack2(a0.w, a2.w);
  wp[ 3 * IN_F / 2] = pack2(a1.x, a3.x);
  wp[ 4 * IN_F / 2] = pack2(a1.y, a3.y);
  wp[ 5 * IN_F / 2] = pack2(a1.z, a3.z);
  wp[ 6 * IN_F / 2] = pack2(a1.w, a3.w);
  wp[ 7 * IN_F / 2] = pack2(b0.y, b2.y);
  wp[ 8 * IN_F / 2] = pack2(b0.z, b2.z);
  wp[ 9 * IN_F / 2] = pack2(b0.w, b2.w);
  wp[10 * IN_F / 2] = pack2(b1.x, b3.x);
  wp[11 * IN_F / 2] = pack2(b1.y, b3.y);
  wp[12 * IN_F / 2] = pack2(b1.z, b3.z);
  wp[13 * IN_F / 2] = pack2(b1.w, b3.w);

  float bsum = b0.x + b2.x;
#pragma unroll
  for (int off = 32; off > 0; off >>= 1) bsum += __shfl_down(bsum, off);
  __shared__ float red[4];
  if ((threadIdx.x & 63) == 0) red[threadIdx.x >> 6] = bsum;
  __syncthreads();
  if (threadIdx.x == 0) atomicAdd(&bias[o], red[0] + red[1] + red[2] + red[3]);
}

// ---------------- feature kernel (feature-major, i-pair): Xf[b][j*1024+i] ----------------
__global__ __launch_bounds__(256) void feat_kernel(const float* __restrict__ x,
                                                   unsigned short* __restrict__ Xf) {
  int idx = blockIdx.x * 256 + threadIdx.x;
  int bb = idx >> 9;
  int i0 = (idx & 511) * 2;
  float2 xv = *reinterpret_cast<const float2*>(x + (size_t)bb * IN_F + i0);
  float s1a, c1a, s1b, c1b;
  sincosf(xv.x, &s1a, &c1a);
  sincosf(xv.y, &s1b, &c1b);
  float sa[KF], ca[KF], sb_[KF], cb[KF];
  sa[1] = s1a; ca[1] = c1a; sb_[1] = s1b; cb[1] = c1b;
#pragma unroll
  for (int k = 2; k < KF; ++k) {
    sa[k]  = sa[k-1]*c1a + ca[k-1]*s1a;
    ca[k]  = ca[k-1]*c1a - sa[k-1]*s1a;
    sb_[k] = sb_[k-1]*c1b + cb[k-1]*s1b;
    cb[k]  = cb[k-1]*c1b - sb_[k-1]*s1b;
  }
  unsigned int* dst = reinterpret_cast<unsigned int*>(Xf + (size_t)bb * KD + i0);
#pragma unroll
  for (int j = 0; j < 7; ++j) dst[j * IN_F / 2]       = pack2(sa[j + 1], sb_[j + 1]);
#pragma unroll
  for (int j = 0; j < 7; ++j) dst[(7 + j) * IN_F / 2] = pack2(ca[j + 1], cb[j + 1]);
}

// ---------------- GEMM: 128x256 tile, 4 waves, 64KB LDS -> 2 blocks/CU ----------------
// Each wave: full 128 M-rows x 64 N-cols (acc[8][4], 0.375 reads/MFMA preserved).
// sA double-buffered (A = Xf, latency-heavy: staged at TILE START, full-tile lead);
// sB single-buffered (W, L2-hot; bf consumed to regs at tile start, staged post-BAR1
// with MFMA-window lead). Two barriers/tile. Cross-block TLP (2 blocks/CU, independent
// barrier domains) provides the port/matrix overlap that intra-block scheduling never
// delivered (R4/R5/R9 evidence). T2 XOR swizzle as R2-R9 (0 conflicts).
__global__ __launch_bounds__(256, 2) void gemm_kernel(const unsigned short* __restrict__ A,
                                                      const unsigned short* __restrict__ Bt,
                                                      float* __restrict__ Cout,
                                                      int use_slab) {
  __shared__ unsigned short sA[2][BM * BK];   // 16 KiB each
  __shared__ unsigned short sB[BN * BK];      // 32 KiB

  const int tid  = threadIdx.x;
  const int wid  = tid >> 6;
  const int lane = tid & 63;
  const int l15  = lane & 15;

  // bijective XCD swizzle: 512 blocks % 8 XCDs == 0; 64 consecutive work items/XCD
  const int bid = blockIdx.x;
  const int s   = (bid & 7) * 64 + (bid >> 3);
  const int z   = s >> 7;          // K-split chunk 0..3 (1 XCD per z... 2 XCDs per chunk)
  const int r   = s & 127;
  const int nt  = r >> 5;          // n-tile slow -> consecutive blocks share W panel in L2
  const int mt  = r & 31;          // m-tile fastest
  const int m0  = mt * BM;
  const int n0  = nt * BN;
  const int fbase = z * KCHUNK;

  // ---- staging addressing (pre-swizzled global source, linear LDS dest) ----
  const int gsw = (lane & 7) ^ (lane >> 3);    // swizzled 16B granule (involution)
  const unsigned short* pA = A  + (size_t)(m0 + (lane >> 3)) * KD + fbase + gsw * 8;
  const unsigned short* pB = Bt + (size_t)(n0 + (lane >> 3)) * KD + fbase + gsw * 8;

  // ---- fragment read addressing (swizzled) ----
  int kfrag[2];
#pragma unroll
  for (int ks = 0; ks < 2; ++ks)
    kfrag[ks] = ((ks * 64 + (lane >> 4) * 16) ^ ((lane & 7) << 4)) >> 1;

  f32x4 acc[8][4] = {};

  // ---- prologue: stage tile 0 (A -> sA[0], B -> sB) ----
#pragma unroll
  for (int j = 0; j < 4; ++j)
    gload_lds16(pA + (size_t)((wid * 4 + j) * 8) * KD, &sA[0][(wid * 4 + j) * 512]);
#pragma unroll
  for (int j = 0; j < 8; ++j)
    gload_lds16(pB + (size_t)((wid * 8 + j) * 8) * KD, &sB[(wid * 8 + j) * 512]);
  asm volatile("s_waitcnt vmcnt(0)" ::: "memory");
  __builtin_amdgcn_s_barrier();

  for (int t = 0; t < NT; ++t) {
    const int c  = t & 1;
    const int cn = c ^ 1;
    const int ktn = (t + 1 < NT) ? (t + 1) * BK : 0;   // dead-wrap keeps ledger uniform
    const unsigned short* sAc = &sA[c][0];

    // stage A(t+1) -> sA[cn]: issued at tile start, waited at tile end (full-tile lead)
#pragma unroll
    for (int j = 0; j < 4; ++j)
      gload_lds16(pA + (size_t)((wid * 4 + j) * 8) * KD + ktn, &sA[cn][(wid * 4 + j) * 512]);

    // read all B frags (both ks: sB is overwritten after BAR1) + all A frags
    short8 bfr[4][2], af0[8], af1[8];
#pragma unroll
    for (int nf = 0; nf < 4; ++nf)
#pragma unroll
      for (int ks = 0; ks < 2; ++ks)
        bfr[nf][ks] = *reinterpret_cast<const short8*>(
            &sB[(wid * 64 + nf * 16 + l15) * 64 + kfrag[ks]]);
#pragma unroll
    for (int mf = 0; mf < 8; ++mf)
      af0[mf] = *reinterpret_cast<const short8*>(sAc + (mf * 16 + l15) * 64 + kfrag[0]);
#pragma unroll
    for (int mf = 0; mf < 8; ++mf)
      af1[mf] = *reinterpret_cast<const short8*>(sAc + (mf * 16 + l15) * 64 + kfrag[1]);

    asm volatile("s_waitcnt lgkmcnt(0)" ::: "memory");
    __builtin_amdgcn_s_barrier();          // BAR1: all waves' reads done -> sB free

    // stage B(t+1) -> sB (L2-hot W: MFMA-window lead suffices)
#pragma unroll
    for (int j = 0; j < 8; ++j)
      gload_lds16(pB + (size_t)((wid * 8 + j) * 8) * KD + ktn, &sB[(wid * 8 + j) * 512]);

    __builtin_amdgcn_s_setprio(1);
#pragma unroll
    for (int mf = 0; mf < 8; ++mf)
#pragma unroll
      for (int nf = 0; nf < 4; ++nf)
        acc[mf][nf] = __builtin_amdgcn_mfma_f32_16x16x32_bf16(af0[mf], bfr[nf][0], acc[mf][nf], 0, 0, 0);
#pragma unroll
    for (int mf = 0; mf < 8; ++mf)
#pragma unroll
      for (int nf = 0; nf < 4; ++nf)
        acc[mf][nf] = __builtin_amdgcn_mfma_f32_16x16x32_bf16(af1[mf], bfr[nf][1], acc[mf][nf], 0, 0, 0);
    __builtin_amdgcn_s_setprio(0);

    asm volatile("s_waitcnt vmcnt(0)" ::: "memory");   // 12 outstanding, all for t+1
    __builtin_amdgcn_s_barrier();          // BAR2: publish sA[cn] + sB
  }

  // ---- epilogue ----
  const int crow = m0 + (lane >> 4) * 4;
  const int ccol = n0 + wid * 64 + l15;
  if (use_slab) {
    float* Cz = Cout + (size_t)z * C_ELEMS;
#pragma unroll
    for (int mf = 0; mf < 8; ++mf)
#pragma unroll
      for (int nf = 0; nf < 4; ++nf)
#pragma unroll
        for (int j = 0; j < 4; ++j)
          Cz[(size_t)(crow + mf * 16 + j) * OUT_F + ccol + nf * 16] = acc[mf][nf][j];
  } else {
#pragma unroll
    for (int mf = 0; mf < 8; ++mf)
#pragma unroll
      for (int nf = 0; nf < 4; ++nf)
#pragma unroll
        for (int j = 0; j < 4; ++j)
          atomicAdd(&Cout[(size_t)(crow + mf * 16 + j) * OUT_F + ccol + nf * 16],
                    acc[mf][nf][j]);
  }
}

// ---------------- K-split slab reduce + bias ----------------
__global__ __launch_bounds__(256) void reduce_kernel(const f32x4* __restrict__ s,
                                                     const float* __restrict__ bias,
                                                     f32x4* __restrict__ y) {
  size_t i = (size_t)blockIdx.x * 256 + threadIdx.x;
  const size_t NQ = C_ELEMS / 4;
  f32x4 v = s[i] + s[i + NQ] + s[i + 2 * NQ] + s[i + 3 * NQ];
  v += reinterpret_cast<const f32x4*>(bias)[i & 255];
  y[i] = v;
}

// ---------------- bias broadcast (atomic-fallback init) ----------------
__global__ __launch_bounds__(256) void binit_kernel(const float* __restrict__ bias,
                                                    f32x4* __restrict__ y) {
  size_t i = (size_t)blockIdx.x * 256 + threadIdx.x;
  y[i] = reinterpret_cast<const f32x4*>(bias)[i & 255];
}

// ---------------- fallback (no workspace): direct f32 evaluation ----------------
__global__ __launch_bounds__(256) void naive_kernel(const float* __restrict__ x,
                                                    const float* __restrict__ a,
                                                    const float* __restrict__ b,
                                                    float* __restrict__ y) {
  int o  = blockIdx.x * 256 + threadIdx.x;
  int bb = blockIdx.y;
  __shared__ float xs[IN_F];
  for (int i = threadIdx.x; i < IN_F; i += 256) xs[i] = x[(size_t)bb * IN_F + i];
  __syncthreads();
  float acc = 0.f;
  for (int i = 0; i < IN_F; ++i) {
    float s1, c1; sincosf(xs[i], &s1, &c1);
    float sk = 0.f, ck = 1.f;
    const float* ap = a + (size_t)o * 8192 + i * KF;
    const float* bp = b + (size_t)o * 8192 + i * KF;
#pragma unroll
    for (int k = 0; k < KF; ++k) {
      acc += sk * ap[k] + ck * bp[k];
      float sn = sk * c1 + ck * s1;
      ck = ck * c1 - sk * s1;
      sk = sn;
    }
  }
  y[(size_t)bb * OUT_F + o] = acc;
}

extern "C" void kernel_launch(void* const* d_in, const int* in_sizes, int n_in,
                              void* d_out, int out_size, void* d_ws, size_t ws_size,
                              hipStream_t stream) {
  (void)in_sizes; (void)n_in; (void)out_size;
  const float* x = (const float*)d_in[0];
  const float* a = (const float*)d_in[1];
  const float* b = (const float*)d_in[2];
  float* y = (float*)d_out;

  const size_t XF_BYTES   = (size_t)BATCH * KD * sizeof(unsigned short);   // 112 MiB
  const size_t W_BYTES    = (size_t)OUT_F * KD * sizeof(unsigned short);   // 28 MiB
  const size_t BIAS_BYTES = (size_t)OUT_F * sizeof(float);                 // 4 KiB
  const size_t SLAB_BYTES = C_ELEMS * sizeof(float) * KSPLIT;              // 64 MiB

  if (ws_size >= XF_BYTES + W_BYTES + BIAS_BYTES) {
    unsigned short* Xf = (unsigned short*)d_ws;
    unsigned short* W  = (unsigned short*)((char*)d_ws + XF_BYTES);
    float* bias        = (float*)((char*)d_ws + XF_BYTES + W_BYTES);
    float* slabs       = (float*)((char*)d_ws + XF_BYTES + W_BYTES + BIAS_BYTES);
    const bool slab = ws_size >= XF_BYTES + W_BYTES + BIAS_BYTES + SLAB_BYTES;

    hipMemsetAsync(bias, 0, BIAS_BYTES, stream);
    wconv_kernel<<<(OUT_F * IN_F / 2) / 256, 256, 0, stream>>>(a, b, W, bias);
    feat_kernel<<<(BATCH * IN_F / 2) / 256, 256, 0, stream>>>(x, Xf);
    if (slab) {
      gemm_kernel<<<dim3((BATCH / BM) * (OUT_F / BN) * KSPLIT), 256, 0, stream>>>(Xf, W, slabs, 1);
      reduce_kernel<<<(int)(C_ELEMS / 4 / 256), 256, 0, stream>>>((const f32x4*)slabs, bias, (f32x4*)y);
    } else {
      binit_kernel<<<(int)(C_ELEMS / 4 / 256), 256, 0, stream>>>(bias, (f32x4*)y);
      gemm_kernel<<<dim3((BATCH / BM) * (OUT_F / BN) * KSPLIT), 256, 0, stream>>>(Xf, W, y, 0);
    }
  } else {
    naive_kernel<<<dim3(OUT_F / 256, BATCH), 256, 0, stream>>>(x, a, b, y);
  }
}

// Round 11
// 168.916 us; speedup vs baseline: 1.7306x; 1.7306x over previous
//
#include <hip/hip_runtime.h>

#define BATCH   4096
#define IN_F    1024
#define OUT_F   1024
#define KF      8
#define KD      14336          /* trimmed GEMM K-dim: (7 sin + 7 cos) * 1024, feature-major */

#define BM 256
#define BN 256
#define BK 64
#define KSPLIT 4
#define KCHUNK (KD/KSPLIT)     /* 3584 */
#define NT (KCHUNK/BK)         /* 56 K-tiles per block (even) */
#define C_ELEMS ((size_t)BATCH * OUT_F)

typedef short short8 __attribute__((ext_vector_type(8)));
typedef float f32x4  __attribute__((ext_vector_type(4)));

// bf16 round-to-nearest-even from f32 (bit pattern in ushort)
__device__ __forceinline__ unsigned short f2bf(float f) {
  union { float f; unsigned int u; } v; v.f = f;
  unsigned int u = v.u;
  unsigned int lsb = (u >> 16) & 1u;
  u += 0x7fffu + lsb;
  return (unsigned short)(u >> 16);
}

__device__ __forceinline__ unsigned int pack2(float lo, float hi) {
  return (unsigned int)f2bf(lo) | ((unsigned int)f2bf(hi) << 16);
}

__device__ __forceinline__ void gload_lds16(const void* g, void* l) {
  __builtin_amdgcn_global_load_lds((const __attribute__((address_space(1))) void*)g,
                                   (__attribute__((address_space(3))) void*)l,
                                   16, 0, 0);
}

// ---------------- W conversion (k=0 trimmed, feature-major, i-pair) + bias ----------------
// Thread per (o, i-pair): 14 coalesced 4B stores; 128B/lane contiguous loads.
__global__ __launch_bounds__(256) void wconv_kernel(const float* __restrict__ a,
                                                    const float* __restrict__ b,
                                                    unsigned short* __restrict__ W,
                                                    float* __restrict__ bias) {
  int idx = blockIdx.x * 256 + threadIdx.x;
  int o  = idx >> 9;
  int i0 = (idx & 511) * 2;
  const float4* ap = reinterpret_cast<const float4*>(a + (size_t)o * 8192 + i0 * 8);
  const float4* bp = reinterpret_cast<const float4*>(b + (size_t)o * 8192 + i0 * 8);
  float4 a0 = ap[0], a1 = ap[1], a2 = ap[2], a3 = ap[3];   // i0: k0-3, k4-7; i0+1: k0-3, k4-7
  float4 b0 = bp[0], b1 = bp[1], b2 = bp[2], b3 = bp[3];

  unsigned int* wp = reinterpret_cast<unsigned int*>(W + (size_t)o * KD + i0);
  wp[ 0 * IN_F / 2] = pack2(a0.y, a2.y);
  wp[ 1 * IN_F / 2] = pack2(a0.z, a2.z);
  wp[ 2 * IN_F / 2] = pack2(a0.w, a2.w);
  wp[ 3 * IN_F / 2] = pack2(a1.x, a3.x);
  wp[ 4 * IN_F / 2] = pack2(a1.y, a3.y);
  wp[ 5 * IN_F / 2] = pack2(a1.z, a3.z);
  wp[ 6 * IN_F / 2] = pack2(a1.w, a3.w);
  wp[ 7 * IN_F / 2] = pack2(b0.y, b2.y);
  wp[ 8 * IN_F / 2] = pack2(b0.z, b2.z);
  wp[ 9 * IN_F / 2] = pack2(b0.w, b2.w);
  wp[10 * IN_F / 2] = pack2(b1.x, b3.x);
  wp[11 * IN_F / 2] = pack2(b1.y, b3.y);
  wp[12 * IN_F / 2] = pack2(b1.z, b3.z);
  wp[13 * IN_F / 2] = pack2(b1.w, b3.w);

  // bias[o] = sum_i b[o,i,0]; one o per block (2 blocks per o), exact f32
  float bsum = b0.x + b2.x;
#pragma unroll
  for (int off = 32; off > 0; off >>= 1) bsum += __shfl_down(bsum, off);
  __shared__ float red[4];
  if ((threadIdx.x & 63) == 0) red[threadIdx.x >> 6] = bsum;
  __syncthreads();
  if (threadIdx.x == 0) atomicAdd(&bias[o], red[0] + red[1] + red[2] + red[3]);
}

// ---------------- feature kernel (feature-major, i-pair): Xf[b][j*1024+i] ----------------
__global__ __launch_bounds__(256) void feat_kernel(const float* __restrict__ x,
                                                   unsigned short* __restrict__ Xf) {
  int idx = blockIdx.x * 256 + threadIdx.x;
  int bb = idx >> 9;
  int i0 = (idx & 511) * 2;
  float2 xv = *reinterpret_cast<const float2*>(x + (size_t)bb * IN_F + i0);
  float s1a, c1a, s1b, c1b;
  sincosf(xv.x, &s1a, &c1a);
  sincosf(xv.y, &s1b, &c1b);
  float sa[KF], ca[KF], sb_[KF], cb[KF];
  sa[1] = s1a; ca[1] = c1a; sb_[1] = s1b; cb[1] = c1b;
#pragma unroll
  for (int k = 2; k < KF; ++k) {
    sa[k]  = sa[k-1]*c1a + ca[k-1]*s1a;
    ca[k]  = ca[k-1]*c1a - sa[k-1]*s1a;
    sb_[k] = sb_[k-1]*c1b + cb[k-1]*s1b;
    cb[k]  = cb[k-1]*c1b - sb_[k-1]*s1b;
  }
  unsigned int* dst = reinterpret_cast<unsigned int*>(Xf + (size_t)bb * KD + i0);
#pragma unroll
  for (int j = 0; j < 7; ++j) dst[j * IN_F / 2]       = pack2(sa[j + 1], sb_[j + 1]);
#pragma unroll
  for (int j = 0; j < 7; ++j) dst[(7 + j) * IN_F / 2] = pack2(ca[j + 1], cb[j + 1]);
}

// ---------------- GEMM: 256x256 tile, 8 waves, 8-phase pipeline (best known: R6/R7) ----
// Counted vmcnt (never 0), 2 stage-loads/phase, T2 swizzle via pre-swizzled source,
// 0 bank conflicts (verified R2-R9). KD=14336, NT=56.
__global__ __launch_bounds__(512, 2) void gemm_kernel(const unsigned short* __restrict__ A,
                                                      const unsigned short* __restrict__ Bt,
                                                      float* __restrict__ Cout,
                                                      int use_slab) {
  __shared__ unsigned short sA[2][BM * BK];   // 32 KiB each
  __shared__ unsigned short sB[2][BN * BK];

  const int tid  = threadIdx.x;
  const int wid  = tid >> 6;
  const int lane = tid & 63;
  const int wm = wid >> 2, wn = wid & 3;

  // bijective XCD swizzle: 256 blocks % 8 XCDs == 0; 32 consecutive work items/XCD
  const int bid = blockIdx.x;
  const int s   = (bid & 7) * 32 + (bid >> 3);
  const int z   = s >> 6;          // K-split chunk 0..3 (2 XCDs per chunk)
  const int mt  = s & 15;          // m-tile fastest -> XCD shares W panels in L2
  const int nt  = (s >> 4) & 3;
  const int m0  = mt * BM;
  const int n0  = nt * BN;
  const int fbase = z * KCHUNK;

  // ---- staging addressing (pre-swizzled global source, linear LDS dest) ----
  const int srow = wid * 8 + (lane >> 3);        // row within a 64-row group
  const int gsw  = (lane & 7) ^ (lane >> 3);     // swizzled 16B granule (involution)
  const unsigned short* pA = A  + (size_t)(m0 + srow) * KD + fbase + gsw * 8;
  const unsigned short* pB = Bt + (size_t)(n0 + srow) * KD + fbase + gsw * 8;
  const int ldst = wid * 512;                    // wave-uniform LDS elem offset in group

  // ---- fragment read addressing (swizzled) ----
  const int l15 = lane & 15;
  int kfrag[2];
#pragma unroll
  for (int ks = 0; ks < 2; ++ks)
    kfrag[ks] = ((ks * 64 + (lane >> 4) * 16) ^ ((lane & 7) << 4)) >> 1;
  const int arow = wm * 128 + l15;
  const int brow = wn * 64 + l15;

  f32x4 acc[8][4] = {};
  short8 bfr[4][2];

  // One phase: reads + 2 stage loads + barrier + 16 MFMA + (vmcnt@q3) + barrier.
#define PHASE(SAC, SBC, Q, STGP, STGDST, G0, KOFF)                              \
  {                                                                             \
    short8 af[2][2];                                                            \
    _Pragma("unroll") for (int i = 0; i < 2; ++i)                               \
      _Pragma("unroll") for (int ks = 0; ks < 2; ++ks)                          \
        af[i][ks] = *reinterpret_cast<const short8*>(                           \
            (SAC) + (arow + (2*(Q)+i)*16)*64 + kfrag[ks]);                      \
    if ((Q) == 0) {                                                             \
      _Pragma("unroll") for (int nf = 0; nf < 4; ++nf)                          \
        _Pragma("unroll") for (int ks = 0; ks < 2; ++ks)                        \
          bfr[nf][ks] = *reinterpret_cast<const short8*>(                       \
              (SBC) + (brow + nf*16)*64 + kfrag[ks]);                           \
    }                                                                           \
    gload_lds16((STGP) + (size_t)((G0)    ) * 64 * KD + (KOFF),                 \
                (STGDST) + ((G0)    ) * 4096 + ldst);                           \
    gload_lds16((STGP) + (size_t)((G0) + 1) * 64 * KD + (KOFF),                 \
                (STGDST) + ((G0) + 1) * 4096 + ldst);                           \
    if ((Q) == 0) asm volatile("s_waitcnt lgkmcnt(8)" ::: "memory");            \
    asm volatile("s_barrier" ::: "memory");                                     \
    __builtin_amdgcn_s_setprio(1);                                              \
    _Pragma("unroll") for (int i = 0; i < 2; ++i)                               \
      _Pragma("unroll") for (int nf = 0; nf < 4; ++nf)                          \
        _Pragma("unroll") for (int ks = 0; ks < 2; ++ks)                        \
          acc[2*(Q)+i][nf] = __builtin_amdgcn_mfma_f32_16x16x32_bf16(           \
              af[i][ks], bfr[nf][ks], acc[2*(Q)+i][nf], 0, 0, 0);               \
    __builtin_amdgcn_s_setprio(0);                                              \
    if ((Q) == 3) asm volatile("s_waitcnt vmcnt(4)" ::: "memory");              \
    asm volatile("s_barrier" ::: "memory");                                     \
  }

  // ---- prologue: stage tile0 (A+B) -> buf0, B(tile1) -> sB[1]; retire tile0 ----
#pragma unroll
  for (int g = 0; g < 4; ++g) {
    gload_lds16(pB + (size_t)g * 64 * KD, &sB[0][g * 4096 + ldst]);
    gload_lds16(pA + (size_t)g * 64 * KD, &sA[0][g * 4096 + ldst]);
  }
#pragma unroll
  for (int g = 0; g < 4; ++g)
    gload_lds16(pB + (size_t)g * 64 * KD + BK, &sB[1][g * 4096 + ldst]);
  asm volatile("s_waitcnt vmcnt(4)" ::: "memory");   // tile0 resident; B(1) in flight
  asm volatile("s_barrier" ::: "memory");

  for (int j = 0; j < NT / 2; ++j) {
    const int kA1 = (2 * j + 1) * BK;                           // tile 2j+1 (always real)
    const int kB2 = (2 * j + 2 < NT) ? (2 * j + 2) * BK : 0;    // tile 2j+2 (dead-wrap at end)
    const int kB3 = (2 * j + 3 < NT) ? (2 * j + 3) * BK : 0;    // tile 2j+3

    // ---- tile 2j from buf0; stage A(2j+1)->sA[1], B(2j+2)->sB[0] ----
    PHASE(&sA[0][0], &sB[0][0], 0, pA, &sA[1][0], 0, kA1)
    PHASE(&sA[0][0], &sB[0][0], 1, pA, &sA[1][0], 2, kA1)
    PHASE(&sA[0][0], &sB[0][0], 2, pB, &sB[0][0], 0, kB2)
    PHASE(&sA[0][0], &sB[0][0], 3, pB, &sB[0][0], 2, kB2)
    // ---- tile 2j+1 from buf1; stage A(2j+2)->sA[0], B(2j+3)->sB[1] ----
    PHASE(&sA[1][0], &sB[1][0], 0, pA, &sA[0][0], 0, kB2)
    PHASE(&sA[1][0], &sB[1][0], 1, pA, &sA[0][0], 2, kB2)
    PHASE(&sA[1][0], &sB[1][0], 2, pB, &sB[1][0], 0, kB3)
    PHASE(&sA[1][0], &sB[1][0], 3, pB, &sB[1][0], 2, kB3)
  }
#undef PHASE

  // ---- epilogue ----
  const int crow = m0 + wm * 128 + (lane >> 4) * 4;
  const int ccol = n0 + wn * 64 + l15;
  if (use_slab) {
    float* Cz = Cout + (size_t)z * C_ELEMS;
#pragma unroll
    for (int mf = 0; mf < 8; ++mf)
#pragma unroll
      for (int nf = 0; nf < 4; ++nf)
#pragma unroll
        for (int j = 0; j < 4; ++j)
          Cz[(size_t)(crow + mf * 16 + j) * OUT_F + ccol + nf * 16] = acc[mf][nf][j];
  } else {
#pragma unroll
    for (int mf = 0; mf < 8; ++mf)
#pragma unroll
      for (int nf = 0; nf < 4; ++nf)
#pragma unroll
        for (int j = 0; j < 4; ++j)
          atomicAdd(&Cout[(size_t)(crow + mf * 16 + j) * OUT_F + ccol + nf * 16],
                    acc[mf][nf][j]);
  }
}

// ---------------- K-split slab reduce + bias: y = s0+s1+s2+s3 + bias[o] ----------------
__global__ __launch_bounds__(256) void reduce_kernel(const f32x4* __restrict__ s,
                                                     const float* __restrict__ bias,
                                                     f32x4* __restrict__ y) {
  size_t i = (size_t)blockIdx.x * 256 + threadIdx.x;
  const size_t NQ = C_ELEMS / 4;
  f32x4 v = s[i] + s[i + NQ] + s[i + 2 * NQ] + s[i + 3 * NQ];
  v += reinterpret_cast<const f32x4*>(bias)[i & 255];   // OUT_F/4 = 256 per row
  y[i] = v;
}

// ---------------- bias broadcast (atomic-fallback init): y[b][o] = bias[o] ----------------
__global__ __launch_bounds__(256) void binit_kernel(const float* __restrict__ bias,
                                                    f32x4* __restrict__ y) {
  size_t i = (size_t)blockIdx.x * 256 + threadIdx.x;
  y[i] = reinterpret_cast<const f32x4*>(bias)[i & 255];
}

// ---------------- fallback (no workspace): direct f32 evaluation ----------------
__global__ __launch_bounds__(256) void naive_kernel(const float* __restrict__ x,
                                                    const float* __restrict__ a,
                                                    const float* __restrict__ b,
                                                    float* __restrict__ y) {
  int o  = blockIdx.x * 256 + threadIdx.x;
  int bb = blockIdx.y;
  __shared__ float xs[IN_F];
  for (int i = threadIdx.x; i < IN_F; i += 256) xs[i] = x[(size_t)bb * IN_F + i];
  __syncthreads();
  float acc = 0.f;
  for (int i = 0; i < IN_F; ++i) {
    float s1, c1; sincosf(xs[i], &s1, &c1);
    float sk = 0.f, ck = 1.f;
    const float* ap = a + (size_t)o * 8192 + i * KF;
    const float* bp = b + (size_t)o * 8192 + i * KF;
#pragma unroll
    for (int k = 0; k < KF; ++k) {
      acc += sk * ap[k] + ck * bp[k];
      float sn = sk * c1 + ck * s1;
      ck = ck * c1 - sk * s1;
      sk = sn;
    }
  }
  y[(size_t)bb * OUT_F + o] = acc;
}

extern "C" void kernel_launch(void* const* d_in, const int* in_sizes, int n_in,
                              void* d_out, int out_size, void* d_ws, size_t ws_size,
                              hipStream_t stream) {
  (void)in_sizes; (void)n_in; (void)out_size;
  const float* x = (const float*)d_in[0];
  const float* a = (const float*)d_in[1];
  const float* b = (const float*)d_in[2];
  float* y = (float*)d_out;

  const size_t XF_BYTES   = (size_t)BATCH * KD * sizeof(unsigned short);   // 112 MiB
  const size_t W_BYTES    = (size_t)OUT_F * KD * sizeof(unsigned short);   // 28 MiB
  const size_t BIAS_BYTES = (size_t)OUT_F * sizeof(float);                 // 4 KiB
  const size_t SLAB_BYTES = C_ELEMS * sizeof(float) * KSPLIT;              // 64 MiB

  if (ws_size >= XF_BYTES + W_BYTES + BIAS_BYTES) {
    unsigned short* Xf = (unsigned short*)d_ws;
    unsigned short* W  = (unsigned short*)((char*)d_ws + XF_BYTES);
    float* bias        = (float*)((char*)d_ws + XF_BYTES + W_BYTES);
    float* slabs       = (float*)((char*)d_ws + XF_BYTES + W_BYTES + BIAS_BYTES);
    const bool slab = ws_size >= XF_BYTES + W_BYTES + BIAS_BYTES + SLAB_BYTES;

    hipMemsetAsync(bias, 0, BIAS_BYTES, stream);
    wconv_kernel<<<(OUT_F * IN_F / 2) / 256, 256, 0, stream>>>(a, b, W, bias);
    feat_kernel<<<(BATCH * IN_F / 2) / 256, 256, 0, stream>>>(x, Xf);
    if (slab) {
      gemm_kernel<<<dim3((BATCH / BM) * (OUT_F / BN) * KSPLIT), 512, 0, stream>>>(Xf, W, slabs, 1);
      reduce_kernel<<<(int)(C_ELEMS / 4 / 256), 256, 0, stream>>>((const f32x4*)slabs, bias, (f32x4*)y);
    } else {
      binit_kernel<<<(int)(C_ELEMS / 4 / 256), 256, 0, stream>>>(bias, (f32x4*)y);
      gemm_kernel<<<dim3((BATCH / BM) * (OUT_F / BN) * KSPLIT), 512, 0, stream>>>(Xf, W, y, 0);
    }
  } else {
    naive_kernel<<<dim3(OUT_F / 256, BATCH), 256, 0, stream>>>(x, a, b, y);
  }
}

// Round 12
// 118.387 us; speedup vs baseline: 2.4693x; 1.4268x over previous
//
#include <hip/hip_runtime.h>

#define BATCH   4096
#define IN_F    1024
#define OUT_F   1024
#define KF      8
#define KD      14336          /* K-dim in i8 elements (= bytes), feature-major, k=0 trimmed */

#define BM 256
#define BN 256
#define BK 64                  /* K per tile (bytes) */
#define KSPLIT 4
#define KCHUNK (KD/KSPLIT)     /* 3584 */
#define NT (KCHUNK/BK)         /* 56 K-tiles per block (even) */
#define C_ELEMS ((size_t)BATCH * OUT_F)

#define QW 1040384.0f          /* 127 * 8192: w stored as raw/8192 -> q = rint(w*QW) */
#define DQ (1.0f/132128768.0f) /* 1/(127*127*8192) */

typedef int   i32x4 __attribute__((ext_vector_type(4)));
typedef float f32x4 __attribute__((ext_vector_type(4)));

__device__ __forceinline__ void gload_lds16(const void* g, void* l) {
  __builtin_amdgcn_global_load_lds((const __attribute__((address_space(1))) void*)g,
                                   (__attribute__((address_space(3))) void*)l,
                                   16, 0, 0);
}

__device__ __forceinline__ unsigned int pack4(int q0, int q1, int q2, int q3) {
  return (unsigned int)(q0 & 255) | ((unsigned int)(q1 & 255) << 8) |
         ((unsigned int)(q2 & 255) << 16) | ((unsigned int)(q3 & 255) << 24);
}

// ---------------- W quantization (k=0 trimmed, feature-major, i-quad) + bias ----------------
// One block per o; thread per 4 i's. Wq[o][j*1024+i] = rint(127*raw_a[o,i,j+1]) (j=0..6),
// rint(127*raw_b[o,i,j-6]) (j=7..13). 14 coalesced 4B stores. bias[o] = sum_i b[o,i,0]
// exact f32 (block covers ALL i of o -> plain store, no atomic/memset).
__global__ __launch_bounds__(256) void wconv_kernel(const float* __restrict__ a,
                                                    const float* __restrict__ b,
                                                    signed char* __restrict__ W,
                                                    float* __restrict__ bias) {
  const int o  = blockIdx.x;
  const int i0 = threadIdx.x * 4;
  const float4* ap = reinterpret_cast<const float4*>(a + (size_t)o * 8192 + i0 * 8);
  const float4* bp = reinterpret_cast<const float4*>(b + (size_t)o * 8192 + i0 * 8);
  union { float4 v[2]; float f[8]; } ua[4], ub[4];
#pragma unroll
  for (int ii = 0; ii < 4; ++ii) {
    ua[ii].v[0] = ap[2 * ii]; ua[ii].v[1] = ap[2 * ii + 1];
    ub[ii].v[0] = bp[2 * ii]; ub[ii].v[1] = bp[2 * ii + 1];
  }
  unsigned int* wp = reinterpret_cast<unsigned int*>(W + (size_t)o * KD + i0);
#pragma unroll
  for (int j = 0; j < 7; ++j) {
    int qa[4], qb[4];
#pragma unroll
    for (int ii = 0; ii < 4; ++ii) {
      qa[ii] = __float2int_rn(ua[ii].f[j + 1] * QW);
      qb[ii] = __float2int_rn(ub[ii].f[j + 1] * QW);
    }
    wp[j       * (IN_F / 4)] = pack4(qa[0], qa[1], qa[2], qa[3]);
    wp[(7 + j) * (IN_F / 4)] = pack4(qb[0], qb[1], qb[2], qb[3]);
  }
  // bias reduce (exact f32): all 1024 i's of this o live in this block
  float bsum = ub[0].f[0] + ub[1].f[0] + ub[2].f[0] + ub[3].f[0];
#pragma unroll
  for (int off = 32; off > 0; off >>= 1) bsum += __shfl_down(bsum, off);
  __shared__ float red[4];
  if ((threadIdx.x & 63) == 0) red[threadIdx.x >> 6] = bsum;
  __syncthreads();
  if (threadIdx.x == 0) bias[o] = red[0] + red[1] + red[2] + red[3];
}

// ---------------- feature kernel (feature-major, i-quad): Xq[b][j*1024+i] i8 ----------------
__global__ __launch_bounds__(256) void feat_kernel(const float* __restrict__ x,
                                                   signed char* __restrict__ Xq) {
  int idx = blockIdx.x * 256 + threadIdx.x;
  int bb = idx >> 8;
  int i0 = (idx & 255) * 4;
  float4 xv = *reinterpret_cast<const float4*>(x + (size_t)bb * IN_F + i0);
  float sv[4][KF], cv[4][KF];
#pragma unroll
  for (int ii = 0; ii < 4; ++ii) {
    float xx = (ii == 0) ? xv.x : (ii == 1) ? xv.y : (ii == 2) ? xv.z : xv.w;
    sincosf(xx, &sv[ii][1], &cv[ii][1]);
#pragma unroll
    for (int k = 2; k < KF; ++k) {
      sv[ii][k] = sv[ii][k-1] * cv[ii][1] + cv[ii][k-1] * sv[ii][1];
      cv[ii][k] = cv[ii][k-1] * cv[ii][1] - sv[ii][k-1] * sv[ii][1];
    }
  }
  unsigned int* dst = reinterpret_cast<unsigned int*>(Xq + (size_t)bb * KD + i0);
#pragma unroll
  for (int j = 0; j < 7; ++j) {
    dst[j * (IN_F / 4)] = pack4(__float2int_rn(127.f * sv[0][j+1]), __float2int_rn(127.f * sv[1][j+1]),
                                __float2int_rn(127.f * sv[2][j+1]), __float2int_rn(127.f * sv[3][j+1]));
    dst[(7 + j) * (IN_F / 4)] = pack4(__float2int_rn(127.f * cv[0][j+1]), __float2int_rn(127.f * cv[1][j+1]),
                                      __float2int_rn(127.f * cv[2][j+1]), __float2int_rn(127.f * cv[3][j+1]));
  }
}

// ---------------- GEMM: i8 256x256 tile, 8 waves, R6-skeleton 2-phase/K-tile pipeline ----
// mfma_i32_16x16x64_i8 (K=64 = full BK row per MFMA). Per phase: 4 af b128 reads
// (+4 bf at Q0, held in regs), 2 gload_lds stage, barrier, 16 MFMA, [vmcnt(2)@Q1],
// barrier -- same barrier/MFMA density and counted-vmcnt ledger as the proven R6/R11
// structure (6 outstanding, retire 4, 2-phase min lead, never 0). LDS 64 KiB.
// T2 swizzle for 64B rows: granule(16B) ^= (r&3)^((r>>2)&3), pre-swizzled global
// source + swizzled ds_read -> 2-way bank aliasing (free, m136). i32 acc is EXACT.
__global__ __launch_bounds__(512, 2) void gemm_kernel(const signed char* __restrict__ A,
                                                      const signed char* __restrict__ Bt,
                                                      int* __restrict__ Cout,
                                                      int use_slab) {
  __shared__ signed char sA[2][BM * BK];   // 16 KiB each
  __shared__ signed char sB[2][BN * BK];

  const int tid  = threadIdx.x;
  const int wid  = tid >> 6;
  const int lane = tid & 63;
  const int wm = wid >> 2, wn = wid & 3;
  const int l15 = lane & 15;

  // bijective XCD swizzle: 256 blocks % 8 XCDs == 0; 32 consecutive work items/XCD
  const int bid = blockIdx.x;
  const int s   = (bid & 7) * 32 + (bid >> 3);
  const int z   = s >> 6;          // K-split chunk 0..3
  const int mt  = s & 15;          // m-tile fastest -> XCD shares W panels in L2
  const int nt  = (s >> 4) & 3;
  const int m0  = mt * BM;
  const int n0  = nt * BN;
  const int fbase = z * KCHUNK;

  // ---- staging addressing: 4 lanes/row (16B granules), 16 rows/wave, 128 rows/gload ----
  const int srow = wid * 16 + (lane >> 2);                 // row 0..127 within group
  const int swz  = ((lane >> 2) & 3) ^ ((lane >> 4) & 3);  // s(row) = (r&3)^((r>>2)&3)
  const int gsrc = (lane & 3) ^ swz;                       // pre-swizzled source granule
  const signed char* pA = A  + (size_t)(m0 + srow) * KD + fbase + gsrc * 16;
  const signed char* pB = Bt + (size_t)(n0 + srow) * KD + fbase + gsrc * 16;
  const int ldst = wid * 1024;                             // byte offset in 8KB group

  // ---- fragment read addressing (swizzled): row r, granule (lane>>4)^s(r&15) ----
  const int rswz = (l15 & 3) ^ ((l15 >> 2) & 3);
  const int kgr  = (((lane >> 4) ^ rswz) & 3) * 16;        // byte offset within 64B row
  const int arowb = (wm * 128 + l15) * BK;                 // byte base, mf stride 16*BK
  const int browb = (wn * 64 + l15) * BK;

  i32x4 acc[8][4] = {};
  i32x4 bfr[4];

  // One phase: 4 af reads (+4 bf at Q0) + 2 stage gloads + barrier + 16 MFMA +
  // [vmcnt(2)@Q1] + barrier.
#define PHASE(SAC, SBC, Q, STGP, STGDST, KOFF)                                  \
  {                                                                             \
    i32x4 af[4];                                                                \
    _Pragma("unroll") for (int f = 0; f < 4; ++f)                               \
      af[f] = *reinterpret_cast<const i32x4*>(                                  \
          (SAC) + arowb + ((Q) * 4 + f) * (16 * BK) + kgr);                     \
    if ((Q) == 0) {                                                             \
      _Pragma("unroll") for (int nf = 0; nf < 4; ++nf)                          \
        bfr[nf] = *reinterpret_cast<const i32x4*>(                              \
            (SBC) + browb + nf * (16 * BK) + kgr);                              \
    }                                                                           \
    gload_lds16((STGP) + (KOFF), (STGDST) + ldst);                              \
    gload_lds16((STGP) + (size_t)128 * KD + (KOFF), (STGDST) + 8192 + ldst);    \
    if ((Q) == 0) asm volatile("s_waitcnt lgkmcnt(4)" ::: "memory");            \
    asm volatile("s_barrier" ::: "memory");                                     \
    __builtin_amdgcn_s_setprio(1);                                              \
    _Pragma("unroll") for (int f = 0; f < 4; ++f)                               \
      _Pragma("unroll") for (int nf = 0; nf < 4; ++nf)                          \
        acc[(Q) * 4 + f][nf] = __builtin_amdgcn_mfma_i32_16x16x64_i8(           \
            af[f], bfr[nf], acc[(Q) * 4 + f][nf], 0, 0, 0);                     \
    __builtin_amdgcn_s_setprio(0);                                              \
    if ((Q) == 1) asm volatile("s_waitcnt vmcnt(2)" ::: "memory");              \
    asm volatile("s_barrier" ::: "memory");                                     \
  }

  // ---- prologue: A(0)->sA[0], B(0)->sB[0], B(1)->sB[1]; retire A0,B0 (B1 in flight) ----
  gload_lds16(pA,                        &sA[0][ldst]);
  gload_lds16(pA + (size_t)128 * KD,     &sA[0][8192 + ldst]);
  gload_lds16(pB,                        &sB[0][ldst]);
  gload_lds16(pB + (size_t)128 * KD,     &sB[0][8192 + ldst]);
  gload_lds16(pB + BK,                   &sB[1][ldst]);
  gload_lds16(pB + (size_t)128 * KD + BK, &sB[1][8192 + ldst]);
  asm volatile("s_waitcnt vmcnt(2)" ::: "memory");
  asm volatile("s_barrier" ::: "memory");

  for (int j = 0; j < NT / 2; ++j) {
    const int kA1 = (2 * j + 1) * BK;                           // tile 2j+1 (always real)
    const int kB2 = (2 * j + 2 < NT) ? (2 * j + 2) * BK : 0;    // dead-wrap at end
    const int kB3 = (2 * j + 3 < NT) ? (2 * j + 3) * BK : 0;

    // tile 2j (buf0): stage A(2j+1)->sA[1], B(2j+2)->sB[0]
    PHASE(&sA[0][0], &sB[0][0], 0, pA, &sA[1][0], kA1)
    PHASE(&sA[0][0], &sB[0][0], 1, pB, &sB[0][0], kB2)
    // tile 2j+1 (buf1): stage A(2j+2)->sA[0], B(2j+3)->sB[1]
    PHASE(&sA[1][0], &sB[1][0], 0, pA, &sA[0][0], kB2)
    PHASE(&sA[1][0], &sB[1][0], 1, pB, &sB[1][0], kB3)
  }
#undef PHASE

  // ---- epilogue (C/D layout dtype-independent: col=l15, row=(lane>>4)*4+jj) ----
  const int crow = m0 + wm * 128 + (lane >> 4) * 4;
  const int ccol = n0 + wn * 64 + l15;
  if (use_slab) {
    int* Cz = Cout + (size_t)z * C_ELEMS;
#pragma unroll
    for (int mf = 0; mf < 8; ++mf)
#pragma unroll
      for (int nf = 0; nf < 4; ++nf)
#pragma unroll
        for (int jj = 0; jj < 4; ++jj)
          Cz[(size_t)(crow + mf * 16 + jj) * OUT_F + ccol + nf * 16] = acc[mf][nf][jj];
  } else {
    float* Cf = reinterpret_cast<float*>(Cout);
#pragma unroll
    for (int mf = 0; mf < 8; ++mf)
#pragma unroll
      for (int nf = 0; nf < 4; ++nf)
#pragma unroll
        for (int jj = 0; jj < 4; ++jj)
          atomicAdd(&Cf[(size_t)(crow + mf * 16 + jj) * OUT_F + ccol + nf * 16],
                    (float)acc[mf][nf][jj] * DQ);
  }
}

// ---------------- K-split i32 slab reduce + dequant + bias ----------------
__global__ __launch_bounds__(256) void reduce_kernel(const i32x4* __restrict__ s,
                                                     const float* __restrict__ bias,
                                                     f32x4* __restrict__ y) {
  size_t i = (size_t)blockIdx.x * 256 + threadIdx.x;
  const size_t NQ = C_ELEMS / 4;
  i32x4 v = s[i] + s[i + NQ] + s[i + 2 * NQ] + s[i + 3 * NQ];
  f32x4 bv = reinterpret_cast<const f32x4*>(bias)[i & 255];   // OUT_F/4 = 256 per row
  f32x4 r;
  r[0] = (float)v[0] * DQ + bv[0];
  r[1] = (float)v[1] * DQ + bv[1];
  r[2] = (float)v[2] * DQ + bv[2];
  r[3] = (float)v[3] * DQ + bv[3];
  y[i] = r;
}

// ---------------- bias broadcast (atomic-fallback init): y[b][o] = bias[o] ----------------
__global__ __launch_bounds__(256) void binit_kernel(const float* __restrict__ bias,
                                                    f32x4* __restrict__ y) {
  size_t i = (size_t)blockIdx.x * 256 + threadIdx.x;
  y[i] = reinterpret_cast<const f32x4*>(bias)[i & 255];
}

// ---------------- fallback (no workspace): direct f32 evaluation ----------------
__global__ __launch_bounds__(256) void naive_kernel(const float* __restrict__ x,
                                                    const float* __restrict__ a,
                                                    const float* __restrict__ b,
                                                    float* __restrict__ y) {
  int o  = blockIdx.x * 256 + threadIdx.x;
  int bb = blockIdx.y;
  __shared__ float xs[IN_F];
  for (int i = threadIdx.x; i < IN_F; i += 256) xs[i] = x[(size_t)bb * IN_F + i];
  __syncthreads();
  float acc = 0.f;
  for (int i = 0; i < IN_F; ++i) {
    float s1, c1; sincosf(xs[i], &s1, &c1);
    float sk = 0.f, ck = 1.f;
    const float* ap = a + (size_t)o * 8192 + i * KF;
    const float* bp = b + (size_t)o * 8192 + i * KF;
#pragma unroll
    for (int k = 0; k < KF; ++k) {
      acc += sk * ap[k] + ck * bp[k];
      float sn = sk * c1 + ck * s1;
      ck = ck * c1 - sk * s1;
      sk = sn;
    }
  }
  y[(size_t)bb * OUT_F + o] = acc;
}

extern "C" void kernel_launch(void* const* d_in, const int* in_sizes, int n_in,
                              void* d_out, int out_size, void* d_ws, size_t ws_size,
                              hipStream_t stream) {
  (void)in_sizes; (void)n_in; (void)out_size;
  const float* x = (const float*)d_in[0];
  const float* a = (const float*)d_in[1];
  const float* b = (const float*)d_in[2];
  float* y = (float*)d_out;

  const size_t XQ_BYTES   = (size_t)BATCH * KD;                            // 56 MiB
  const size_t WQ_BYTES   = (size_t)OUT_F * KD;                            // 14 MiB
  const size_t BIAS_BYTES = (size_t)OUT_F * sizeof(float);                 // 4 KiB
  const size_t SLAB_BYTES = C_ELEMS * sizeof(int) * KSPLIT;                // 64 MiB

  if (ws_size >= XQ_BYTES + WQ_BYTES + BIAS_BYTES) {
    signed char* Xq = (signed char*)d_ws;
    signed char* Wq = (signed char*)d_ws + XQ_BYTES;
    float* bias     = (float*)((char*)d_ws + XQ_BYTES + WQ_BYTES);
    int* slabs      = (int*)((char*)d_ws + XQ_BYTES + WQ_BYTES + BIAS_BYTES);
    const bool slab = ws_size >= XQ_BYTES + WQ_BYTES + BIAS_BYTES + SLAB_BYTES;

    wconv_kernel<<<OUT_F, 256, 0, stream>>>(a, b, Wq, bias);
    feat_kernel<<<(BATCH * IN_F / 4) / 256, 256, 0, stream>>>(x, Xq);
    if (slab) {
      gemm_kernel<<<dim3((BATCH / BM) * (OUT_F / BN) * KSPLIT), 512, 0, stream>>>(Xq, Wq, slabs, 1);
      reduce_kernel<<<(int)(C_ELEMS / 4 / 256), 256, 0, stream>>>((const i32x4*)slabs, bias, (f32x4*)y);
    } else {
      binit_kernel<<<(int)(C_ELEMS / 4 / 256), 256, 0, stream>>>(bias, (f32x4*)y);
      gemm_kernel<<<dim3((BATCH / BM) * (OUT_F / BN) * KSPLIT), 512, 0, stream>>>(Xq, Wq, (int*)y, 0);
    }
  } else {
    naive_kernel<<<dim3(OUT_F / 256, BATCH), 256, 0, stream>>>(x, a, b, y);
  }
}